// Round 9
// baseline (385.139 us; speedup 1.0000x reference)
//
#include <hip/hip_runtime.h>
#include <hip/hip_bf16.h>
#include <cstdint>
#include <cstddef>

// JacobiKANLinear: DEGREE=5, A=B=1.0. Inputs fp32, output fp32 (HW-verified r1/r2/r5).
// v10 = v9 (monomial basis + 208B As rows) with B staging switched from
// global_load_lds (DMA) to reg-staged loads + ds_write (T14):
//   r8 falsification: SQ_LDS_BANK_CONFLICT = 1.887e7 EXACTLY across v3..v9
//   (including v5 with half the ds_reads and v9 with changed write stride) —
//   only the gload_lds B-staging was constant => ~24 conflict-cyc per DMA
//   burst, unfixable by layout. Reg-staging removes it AND lets Bs be
//   single-buffered (write window is barrier-sandwiched like As):
//   LDS 51200 B -> 3 blocks/CU (was 2).
#define BATCH   8192
#define IN_F    1024
#define OUT_F   1024
#define KAUG    (6 * 1024)   // k = i*6 + m ; m=0 -> base weight (silu), m=1..5 -> t^m
#define NSTEP   64           // K-steps: 6144 / 96

typedef __bf16 bf16x8 __attribute__((ext_vector_type(8)));
typedef float  f32x4  __attribute__((ext_vector_type(4)));

// Workspace layout (bytes), ~12.6 MB:
static constexpr size_t WAUG_B    = (size_t)OUT_F * KAUG * 2;        // 12,582,912
static constexpr size_t BIAS2_OFF = WAUG_B;                          // 4 KB f32

// Monomial coefficients of the reference's P_j recurrence (A=B=1, exact):
//   P1 = 2t ; P2 = (16/15)t^2 - 2/5 ; P3 = (4/7)t^3 - (15/14)t
//   P4 = (32/105)t^4 - (988/945)t^2 + 8/45
//   P5 = (16/99)t^5 - 0.8141735129 t^3 + 0.5812890813 t
constexpr float M1_1 = 2.0f;
constexpr float M3_1 = -1.0714285714f;   // -15/14
constexpr float M5_1 =  0.5812890813f;
constexpr float M2_2 =  1.0666666667f;   // 16/15
constexpr float M4_2 = -1.0455026455f;   // -988/945
constexpr float M3_3 =  0.5714285714f;   // 4/7
constexpr float M5_3 = -0.8141735129f;
constexpr float M4_4 =  0.3047619048f;   // 32/105
constexpr float M5_5 =  0.1616161616f;   // 16/99
constexpr float M2_0 = -0.4f;            // -2/5
constexpr float M4_0 =  0.1777777778f;   // 8/45

__device__ __forceinline__ unsigned short f2bf(float f)
{
    __hip_bfloat16 h = __float2bfloat16(f);
    return *(unsigned short*)&h;
}
__device__ __forceinline__ unsigned pack2(float lo, float hi)   // RNE (prep path)
{
    return (unsigned)f2bf(lo) | ((unsigned)f2bf(hi) << 16);
}
// Fast packed conversion: D[15:0]=bf16(lo), D[31:16]=bf16(hi).
__device__ __forceinline__ unsigned cvt_pk(float lo, float hi)
{
    unsigned r;
    asm("v_cvt_pk_bf16_f32 %0, %1, %2" : "=v"(r) : "v"(lo), "v"(hi));
    return r;
}

// ---------------- prep: weights + bias fold + basis change (1024 blocks) ------
__global__ void prep_w(const float* __restrict__ W,
                       const float* __restrict__ C,
                       const float* __restrict__ bias,
                       __hip_bfloat16* __restrict__ Waug,
                       float* __restrict__ bias2)
{
    const int o = blockIdx.x;
    const int tid = threadIdx.x;

    __shared__ __align__(16) float cs[IN_F * 6];   // 24 KB
    __shared__ float red[4];

    // ---- coalesced C-row load: 6 x float4 per thread, lane-consecutive ----
    const float4* C4  = (const float4*)(C + (size_t)o * IN_F * 6);
    float4*       cs4 = (float4*)cs;
#pragma unroll
    for (int k = 0; k < 6; ++k) cs4[tid + k * 256] = C4[tid + k * 256];

    const float4 wv = ((const float4*)(W + (size_t)o * IN_F))[tid];
    const float w4[4] = {wv.x, wv.y, wv.z, wv.w};

    __syncthreads();

    // ---- per-thread gather from LDS: 24 floats = C[o][i..i+3][0..5] ----
    float f[24];
#pragma unroll
    for (int q = 0; q < 6; ++q) {
        const float4 v = cs4[tid * 6 + q];
        f[q * 4 + 0] = v.x; f[q * 4 + 1] = v.y; f[q * 4 + 2] = v.z; f[q * 4 + 3] = v.w;
    }

    unsigned pk[12];
    float s = 0.f;
#pragma unroll
    for (int q = 0; q < 4; ++q) {
        const float c0 = f[q * 6 + 0], c1 = f[q * 6 + 1], c2 = f[q * 6 + 2];
        const float c3 = f[q * 6 + 3], c4 = f[q * 6 + 4], c5 = f[q * 6 + 5];
        const float cp1 = M1_1 * c1 + M3_1 * c3 + M5_1 * c5;
        const float cp2 = M2_2 * c2 + M4_2 * c4;
        const float cp3 = M3_3 * c3 + M5_3 * c5;
        const float cp4 = M4_4 * c4;
        const float cp5 = M5_5 * c5;
        s += c0 + M2_0 * c2 + M4_0 * c4;            // constant terms -> bias
        pk[q * 3 + 0] = pack2(w4[q], cp1);
        pk[q * 3 + 1] = pack2(cp2,   cp3);
        pk[q * 3 + 2] = pack2(cp4,   cp5);
    }

#pragma unroll
    for (int off = 32; off > 0; off >>= 1) s += __shfl_down(s, off, 64);
    if ((tid & 63) == 0) red[tid >> 6] = s;

    __syncthreads();                               // everyone done reading cs
    uint4* csU = (uint4*)cs;
    csU[tid * 3 + 0] = make_uint4(pk[0], pk[1], pk[2],  pk[3]);
    csU[tid * 3 + 1] = make_uint4(pk[4], pk[5], pk[6],  pk[7]);
    csU[tid * 3 + 2] = make_uint4(pk[8], pk[9], pk[10], pk[11]);
    __syncthreads();

    uint4* out4 = (uint4*)(Waug + (size_t)o * KAUG);
#pragma unroll
    for (int k = 0; k < 3; ++k) out4[tid + k * 256] = csU[tid + k * 256];

    if (tid == 0) bias2[o] = bias[o] + red[0] + red[1] + red[2] + red[3];
}

// ---------------- fused GEMM v10 ----------------
// 128x128 tile, BK=96 (16 inputs), 256 threads (2x2 waves, 64x64/wave).
// A: expanded on the fly -> ds_write bf16 into As (208 B rows, both-side
//    conflict-free: write slot (5(l>>1)+6(l&1)+j)%8 uniform, read (5mr+quad)%8
//    uniform).
// B: REG-STAGED (v10): breg[6] global_load_dwordx4 issued post-barrier (aged
//    by compute+expand ~1500+ cyc), ds_write_b128 in the barrier-sandwiched
//    window (slot = lane%8, conflict-free). Bs SINGLE-buffered.
// LDS: As 26624 + Bs 24576 = 51200 -> 3 blocks/CU.
// Step t: expand(t)->pk | b1 | write As(t), write Bs<-breg(B(t)) | b2 |
//         issue breg<-B(t+1), xc<-x(t+1) ; compute MFMA(t).
#define AS_B    26624                 // As bytes (128 rows x 208 B)
#define BS_B    24576                 // Bs bytes (128 rows x 192 B)
#define SMEM_B  (AS_B + BS_B)         // 51200

__global__ __launch_bounds__(256, 3)
void gemm_kan(const float* __restrict__ X,
              const __hip_bfloat16* __restrict__ Waug,
              const float* __restrict__ bias2,
              float* __restrict__ out)
{
    extern __shared__ __align__(16) char smem[];   // [As 26624 | Bs 24576]

    const int tid  = threadIdx.x;
    const int lane = tid & 63;
    const int wave = tid >> 6;
    const int wm = wave & 1, wn = wave >> 1;
    const int mBase = blockIdx.x * 128;            // M fastest -> XCD = bx % 8
    const int nBase = blockIdx.y * 128;

    // ---- x source for expansion: row tid>>1, inputs (tid&1)*8 .. +7 ----
    const float* gx = X + (size_t)(mBase + (tid >> 1)) * IN_F + (tid & 1) * 8;
    char* const aw = smem + (tid >> 1) * 208 + (tid & 1) * 96;   // thread's 96 B in As

    // ---- B staging: 6 x 16B chunks per thread (global src -> breg -> Bs) ----
    const __hip_bfloat16* gB[6]; char* bW[6];
#pragma unroll
    for (int q = 0; q < 6; ++q) {
        const int ci = (q * 4 + wave) * 64 + lane;   // 16B-chunk index in 24 KB tile
        const int br = ci / 12, bc = ci - br * 12;   // row 0..127, chunk 0..11
        gB[q] = Waug + (size_t)(nBase + br) * KAUG + bc * 8;
        bW[q] = smem + AS_B + (size_t)ci * 16;       // linear: slot = lane%8, clean
    }

    // ---- fragment offsets (16B-vector units) ----
    const int quad = lane >> 4, mr = lane & 15;
    const int aoff = (wm * 64 + mr) * 13 + quad;               // 13 chunks/row
    const int boff = (AS_B / 16) + (wn * 64 + mr) * 12 + quad; // B rows: 12 chunks

    f32x4 acc[4][4] = {};
    uint4 breg[6];

    // ---- prologue: x(0), B(0) issued; loop body handles the rest ----
    float4 xc0 = *(const float4*)(gx);
    float4 xc1 = *(const float4*)(gx + 4);
#pragma unroll
    for (int q = 0; q < 6; ++q) breg[q] = *(const uint4*)(gB[q]);

#pragma unroll 1
    for (int t = 0; t < NSTEP; ++t) {
        // ---- expand 8 inputs -> [silu, t, t^2..t^5] bf16 (~16 ops/elem) ----
        const float xs[8] = {xc0.x, xc0.y, xc0.z, xc0.w, xc1.x, xc1.y, xc1.z, xc1.w};
        unsigned pk[24];
#pragma unroll
        for (int e = 0; e < 8; ++e) {
            const float x  = xs[e];
            // v = e^-x, clamped so u = v*v stays finite (x <= -43: sig->0, t->-1)
            const float v  = __expf(fminf(-x, 43.f));
            const float sg = __builtin_amdgcn_rcpf(1.f + v);
            const float s  = x * sg;                  // silu(x) = x * sigmoid(x)
            const float u  = v * v;                   // e^-2x
            const float tt = (1.f - u) * __builtin_amdgcn_rcpf(1.f + u);   // tanh(x)
            const float t2 = tt * tt;
            const float t3 = t2 * tt;
            const float t4 = t2 * t2;
            const float t5 = t4 * tt;
            pk[e * 3 + 0] = cvt_pk(s,  tt);
            pk[e * 3 + 1] = cvt_pk(t2, t3);
            pk[e * 3 + 2] = cvt_pk(t4, t5);
        }
        __syncthreads();   // b1: reads of As(t-1)/Bs(t-1) complete; vmem aged

        // ---- write window: As(t) + Bs <- breg (B(t)) ----
#pragma unroll
        for (int j = 0; j < 6; ++j)
            *(uint4*)(aw + j * 16) = make_uint4(pk[j * 4], pk[j * 4 + 1],
                                                pk[j * 4 + 2], pk[j * 4 + 3]);
#pragma unroll
        for (int q = 0; q < 6; ++q) *(uint4*)(bW[q]) = breg[q];
        __syncthreads();   // b2: As(t)/Bs(t) visible

        // ---- issue next-step loads FIRST: they age through compute+expand ----
        if (t + 1 < NSTEP) {
#pragma unroll
            for (int q = 0; q < 6; ++q)
                breg[q] = *(const uint4*)(gB[q] + (size_t)(t + 1) * 96);
            xc0 = *(const float4*)(gx + (size_t)(t + 1) * 16);
            xc1 = *(const float4*)(gx + (size_t)(t + 1) * 16 + 4);
        }

        // ---- compute: 3 k-chunks x 16 MFMA from As + Bs ----
        const bf16x8* V = (const bf16x8*)smem;
#pragma unroll
        for (int kc = 0; kc < 3; ++kc) {
            bf16x8 a[4], b[4];
#pragma unroll
            for (int t4 = 0; t4 < 4; ++t4) a[t4] = V[aoff + t4 * 208 + kc * 4];
#pragma unroll
            for (int t4 = 0; t4 < 4; ++t4) b[t4] = V[boff + t4 * 192 + kc * 4];
#pragma unroll
            for (int i = 0; i < 4; ++i)
#pragma unroll
                for (int jj = 0; jj < 4; ++jj)
                    acc[i][jj] = __builtin_amdgcn_mfma_f32_16x16x32_bf16(a[i], b[jj], acc[i][jj], 0, 0, 0);
        }
    }

    // ---- direct-store epilogue; C/D map hardcoded (m89-verified: row_in_16 =
    // quad*4+r, col = mr — matched the probe every measured run) ----
#pragma unroll
    for (int i = 0; i < 4; ++i) {
#pragma unroll
        for (int jj = 0; jj < 4; ++jj) {
            const int col = nBase + wn * 64 + jj * 16 + mr;
            const float b2 = bias2[col];
#pragma unroll
            for (int r = 0; r < 4; ++r) {
                const int row = mBase + wm * 64 + i * 16 + quad * 4 + r;
                out[(size_t)row * OUT_F + col] = acc[i][jj][r] + b2;
            }
        }
    }
}

// ---------------- launch ----------------

extern "C" void kernel_launch(void* const* d_in, const int* in_sizes, int n_in,
                              void* d_out, int out_size, void* d_ws, size_t ws_size,
                              hipStream_t stream)
{
    (void)out_size; (void)ws_size;
    const float* x    = (const float*)d_in[0];
    const float* W    = (const float*)d_in[1];
    const float* C    = (const float*)d_in[2];
    const float* bias = (const float*)d_in[3];
    for (int i = 0; i < n_in; ++i) {
        if      (in_sizes[i] == BATCH * IN_F)     x    = (const float*)d_in[i];
        else if (in_sizes[i] == OUT_F * IN_F)     W    = (const float*)d_in[i];
        else if (in_sizes[i] == OUT_F * IN_F * 6) C    = (const float*)d_in[i];
        else if (in_sizes[i] == OUT_F)            bias = (const float*)d_in[i];
    }
    float* out = (float*)d_out;
    char* ws = (char*)d_ws;
    __hip_bfloat16* Waug  = (__hip_bfloat16*)ws;
    float*          bias2 = (float*)(ws + BIAS2_OFF);

    // 50 KB dynamic LDS (<= 64 KB default, but keep the opt-in for safety).
    static bool smem_attr_done = false;
    if (!smem_attr_done) {
        (void)hipFuncSetAttribute((const void*)gemm_kan,
                                  hipFuncAttributeMaxDynamicSharedMemorySize,
                                  SMEM_B);
        smem_attr_done = true;
    }

    prep_w<<<dim3(OUT_F), dim3(256), 0, stream>>>(W, C, bias, Waug, bias2);
    gemm_kan<<<dim3(BATCH / 128, OUT_F / 128), dim3(256), SMEM_B, stream>>>(
        x, Waug, bias2, out);
}

// Round 10
// 209.964 us; speedup vs baseline: 1.8343x; 1.8343x over previous
//
#include <hip/hip_runtime.h>
#include <hip/hip_bf16.h>
#include <cstdint>
#include <cstddef>

// JacobiKANLinear: DEGREE=5, A=B=1.0. Inputs fp32, output fp32 (HW-verified r1/r2/r5).
// v11: single-barrier fused GEMM. r9 falsifications: (1) SQ_LDS_BANK_CONFLICT
// 1.887e7 = 4cyc x every b128 wave-instr (structural, NOT conflicts — constant
// with gload_lds removed); (2) reg-carry across barriers => scratch (v7/v10).
// => restructure: 256x128 tile, 8 waves, As+Bs FULL double-buffer (152 KB LDS,
// 1 block/CU), ONE __syncthreads/step; stage/MFMA/expand/write all in one
// region (pk & xc never cross a barrier). B bytes now feed 4 wm-groups
// (2x reuse) -> LDS instr/FLOP -25%.
#define BATCH   8192
#define IN_F    1024
#define OUT_F   1024
#define KAUG    (6 * 1024)   // k = i*6 + m ; m=0 -> base weight (silu), m=1..5 -> t^m
#define NSTEP   64           // K-steps: 6144 / 96

typedef __bf16 bf16x8 __attribute__((ext_vector_type(8)));
typedef float  f32x4  __attribute__((ext_vector_type(4)));

// Workspace layout (bytes), ~12.6 MB:
static constexpr size_t WAUG_B    = (size_t)OUT_F * KAUG * 2;        // 12,582,912
static constexpr size_t BIAS2_OFF = WAUG_B;                          // 4 KB f32

// Monomial coefficients of the reference's P_j recurrence (A=B=1, exact):
constexpr float M1_1 = 2.0f;
constexpr float M3_1 = -1.0714285714f;   // -15/14
constexpr float M5_1 =  0.5812890813f;
constexpr float M2_2 =  1.0666666667f;   // 16/15
constexpr float M4_2 = -1.0455026455f;   // -988/945
constexpr float M3_3 =  0.5714285714f;   // 4/7
constexpr float M5_3 = -0.8141735129f;
constexpr float M4_4 =  0.3047619048f;   // 32/105
constexpr float M5_5 =  0.1616161616f;   // 16/99
constexpr float M2_0 = -0.4f;            // -2/5
constexpr float M4_0 =  0.1777777778f;   // 8/45

__device__ __forceinline__ unsigned short f2bf(float f)
{
    __hip_bfloat16 h = __float2bfloat16(f);
    return *(unsigned short*)&h;
}
__device__ __forceinline__ unsigned pack2(float lo, float hi)   // RNE (prep path)
{
    return (unsigned)f2bf(lo) | ((unsigned)f2bf(hi) << 16);
}
__device__ __forceinline__ unsigned cvt_pk(float lo, float hi)
{
    unsigned r;
    asm("v_cvt_pk_bf16_f32 %0, %1, %2" : "=v"(r) : "v"(lo), "v"(hi));
    return r;
}

// ---------------- prep: weights + bias fold + basis change (v9 verbatim) ------
__global__ void prep_w(const float* __restrict__ W,
                       const float* __restrict__ C,
                       const float* __restrict__ bias,
                       __hip_bfloat16* __restrict__ Waug,
                       float* __restrict__ bias2)
{
    const int o = blockIdx.x;
    const int tid = threadIdx.x;

    __shared__ __align__(16) float cs[IN_F * 6];   // 24 KB
    __shared__ float red[4];

    const float4* C4  = (const float4*)(C + (size_t)o * IN_F * 6);
    float4*       cs4 = (float4*)cs;
#pragma unroll
    for (int k = 0; k < 6; ++k) cs4[tid + k * 256] = C4[tid + k * 256];

    const float4 wv = ((const float4*)(W + (size_t)o * IN_F))[tid];
    const float w4[4] = {wv.x, wv.y, wv.z, wv.w};

    __syncthreads();

    float f[24];
#pragma unroll
    for (int q = 0; q < 6; ++q) {
        const float4 v = cs4[tid * 6 + q];
        f[q * 4 + 0] = v.x; f[q * 4 + 1] = v.y; f[q * 4 + 2] = v.z; f[q * 4 + 3] = v.w;
    }

    unsigned pk[12];
    float s = 0.f;
#pragma unroll
    for (int q = 0; q < 4; ++q) {
        const float c0 = f[q * 6 + 0], c1 = f[q * 6 + 1], c2 = f[q * 6 + 2];
        const float c3 = f[q * 6 + 3], c4 = f[q * 6 + 4], c5 = f[q * 6 + 5];
        const float cp1 = M1_1 * c1 + M3_1 * c3 + M5_1 * c5;
        const float cp2 = M2_2 * c2 + M4_2 * c4;
        const float cp3 = M3_3 * c3 + M5_3 * c5;
        const float cp4 = M4_4 * c4;
        const float cp5 = M5_5 * c5;
        s += c0 + M2_0 * c2 + M4_0 * c4;            // constant terms -> bias
        pk[q * 3 + 0] = pack2(w4[q], cp1);
        pk[q * 3 + 1] = pack2(cp2,   cp3);
        pk[q * 3 + 2] = pack2(cp4,   cp5);
    }

#pragma unroll
    for (int off = 32; off > 0; off >>= 1) s += __shfl_down(s, off, 64);
    if ((tid & 63) == 0) red[tid >> 6] = s;

    __syncthreads();
    uint4* csU = (uint4*)cs;
    csU[tid * 3 + 0] = make_uint4(pk[0], pk[1], pk[2],  pk[3]);
    csU[tid * 3 + 1] = make_uint4(pk[4], pk[5], pk[6],  pk[7]);
    csU[tid * 3 + 2] = make_uint4(pk[8], pk[9], pk[10], pk[11]);
    __syncthreads();

    uint4* out4 = (uint4*)(Waug + (size_t)o * KAUG);
#pragma unroll
    for (int k = 0; k < 3; ++k) out4[tid + k * 256] = csU[tid + k * 256];

    if (tid == 0) bias2[o] = bias[o] + red[0] + red[1] + red[2] + red[3];
}

// ---------------- fused GEMM v11 ----------------
// 256x128 tile, BK=96 (16 inputs), 512 threads = 8 waves (4M x 2N), 64x64/wave.
// LDS 155648 B = As0|As1 (256 rows x 208 B each) + Bs0|Bs1 (128 rows x 192 B):
// 1 block/CU (AITER fmha precedent: 160 KB LDS works on gfx950).
// Step t (ONE barrier): [stage B(t+1)->Bs[(t+1)&1] via gload_lds; load x(t+1);
//   MFMA(t) from As[t&1]/Bs[t&1]; expand(t+1)->pk->ds_write As[(t+1)&1]]
//   -> __syncthreads (drains: B(t+1) vmcnt aged one full step; As lgkm).
// WAR: buffer (t+1)&1 was last read in step t-1, i.e. before the barrier that
// precedes these writes. pk/xc produced+consumed in-region (spill law safe).
// As stride 208 (13 chunks, 5 mod 8 coprime): write slots (5(l>>1)+6(l&1)+j)%8
// and read slots (5mr+quad)%8 both uniform. Bs 192: read (4mr+quad)%8 uniform.
__device__ __forceinline__ void async_load16(const void* g, void* l)
{
    __builtin_amdgcn_global_load_lds(
        (const __attribute__((address_space(1))) void*)g,
        (__attribute__((address_space(3))) void*)l,
        16, 0, 0);
}

#define ASB_B   53248                 // per As buffer (256 rows x 208 B)
#define BSB_B   24576                 // per Bs buffer (128 rows x 192 B)
#define AS_TOT  (2 * ASB_B)           // 106496
#define SMEM_B  (AS_TOT + 2 * BSB_B)  // 155648

__global__ __launch_bounds__(512, 2)
void gemm_kan(const float* __restrict__ X,
              const __hip_bfloat16* __restrict__ Waug,
              const float* __restrict__ bias2,
              float* __restrict__ out)
{
    extern __shared__ __align__(16) char smem[];   // [As0 | As1 | Bs0 | Bs1]

    const int tid  = threadIdx.x;
    const int lane = tid & 63;
    const int wave = tid >> 6;                     // 0..7
    const int wm = wave >> 1, wn = wave & 1;       // 4 M-groups x 2 N-groups
    const int mBase = blockIdx.x * 256;            // bx fastest -> XCD = bx % 8
    const int nBase = blockIdx.y * 128;

    // ---- x source: row tid>>1 (0..255), inputs (tid&1)*8 .. +7 ----
    const float* gx = X + (size_t)(mBase + (tid >> 1)) * IN_F + (tid & 1) * 8;
    char* const aw = smem + (tid >> 1) * 208 + (tid & 1) * 96;   // + asel*ASB_B

    // ---- B staging: 3 x 16B chunks per thread via gload_lds (linear dest) ----
    const __hip_bfloat16* gB[3]; int lB[3];
#pragma unroll
    for (int q = 0; q < 3; ++q) {
        const int ci = (q * 8 + wave) * 64 + lane;   // chunk idx in 24 KB tile
        const int br = ci / 12, bc = ci - br * 12;   // row 0..127, chunk 0..11
        gB[q] = Waug + (size_t)(nBase + br) * KAUG + bc * 8;
        lB[q] = AS_TOT + (q * 8 + wave) * 1024;      // + lane*16 added by HW
    }

    // ---- fragment offsets (16B-vector units) ----
    const int quad = lane >> 4, mr = lane & 15;
    const int aoff = (wm * 64 + mr) * 13 + quad;                  // As: 13 chunks/row
    const int boff = (AS_TOT / 16) + (wn * 64 + mr) * 12 + quad;  // Bs: 12 chunks/row

    f32x4 acc[4][4] = {};

    // ---- prologue: B(0)->Bs0; expand(0)->As0; one drain barrier ----
    {
#pragma unroll
        for (int q = 0; q < 3; ++q) async_load16(gB[q], smem + lB[q]);
        const float4 x0 = *(const float4*)(gx);
        const float4 x1 = *(const float4*)(gx + 4);
        const float xs[8] = {x0.x, x0.y, x0.z, x0.w, x1.x, x1.y, x1.z, x1.w};
        unsigned pk[24];
#pragma unroll
        for (int e = 0; e < 8; ++e) {
            const float x  = xs[e];
            const float v  = __expf(fminf(-x, 43.f));
            const float sg = __builtin_amdgcn_rcpf(1.f + v);
            const float s  = x * sg;
            const float u  = v * v;
            const float tt = (1.f - u) * __builtin_amdgcn_rcpf(1.f + u);
            const float t2 = tt * tt, t3 = t2 * tt, t4 = t2 * t2, t5 = t4 * tt;
            pk[e * 3 + 0] = cvt_pk(s,  tt);
            pk[e * 3 + 1] = cvt_pk(t2, t3);
            pk[e * 3 + 2] = cvt_pk(t4, t5);
        }
#pragma unroll
        for (int j = 0; j < 6; ++j)
            *(uint4*)(aw + j * 16) = make_uint4(pk[j * 4], pk[j * 4 + 1],
                                                pk[j * 4 + 2], pk[j * 4 + 3]);
    }
    __syncthreads();

#pragma unroll 1
    for (int t = 0; t < NSTEP; ++t) {
        // ---- stage B(t+1) + load x(t+1) (issued first: age the whole step) ----
        if (t + 1 < NSTEP) {
            const int nsel = (t + 1) & 1;
#pragma unroll
            for (int q = 0; q < 3; ++q)
                async_load16(gB[q] + (size_t)(t + 1) * 96,
                             smem + lB[q] + nsel * BSB_B);
        }
        float4 xn0 = {}, xn1 = {};
        if (t + 1 < NSTEP) {
            xn0 = *(const float4*)(gx + (size_t)(t + 1) * 16);
            xn1 = *(const float4*)(gx + (size_t)(t + 1) * 16 + 4);
        }

        // ---- MFMA(t): 3 k-chunks x 16 from As[t&1], Bs[t&1] ----
        const bf16x8* V = (const bf16x8*)smem;
        const int ab = aoff + (t & 1) * (ASB_B / 16);
        const int bb = boff + (t & 1) * (BSB_B / 16);
#pragma unroll
        for (int kc = 0; kc < 3; ++kc) {
            bf16x8 a[4], b[4];
#pragma unroll
            for (int t4 = 0; t4 < 4; ++t4) a[t4] = V[ab + t4 * 208 + kc * 4];
#pragma unroll
            for (int t4 = 0; t4 < 4; ++t4) b[t4] = V[bb + t4 * 192 + kc * 4];
#pragma unroll
            for (int i = 0; i < 4; ++i)
#pragma unroll
                for (int jj = 0; jj < 4; ++jj)
                    acc[i][jj] = __builtin_amdgcn_mfma_f32_16x16x32_bf16(
                        a[i], b[jj], acc[i][jj], 0, 0, 0);
        }

        // ---- expand(t+1) -> As[(t+1)&1] (VALU overlaps MFMA; same region) ----
        if (t + 1 < NSTEP) {
            const float xs[8] = {xn0.x, xn0.y, xn0.z, xn0.w, xn1.x, xn1.y, xn1.z, xn1.w};
            unsigned pk[24];
#pragma unroll
            for (int e = 0; e < 8; ++e) {
                const float x  = xs[e];
                const float v  = __expf(fminf(-x, 43.f));
                const float sg = __builtin_amdgcn_rcpf(1.f + v);
                const float s  = x * sg;                  // silu
                const float u  = v * v;                   // e^-2x
                const float tt = (1.f - u) * __builtin_amdgcn_rcpf(1.f + u);
                const float t2 = tt * tt, t3 = t2 * tt, t4 = t2 * t2, t5 = t4 * tt;
                pk[e * 3 + 0] = cvt_pk(s,  tt);
                pk[e * 3 + 1] = cvt_pk(t2, t3);
                pk[e * 3 + 2] = cvt_pk(t4, t5);
            }
            char* const asd = aw + ((t + 1) & 1) * ASB_B;
#pragma unroll
            for (int j = 0; j < 6; ++j)
                *(uint4*)(asd + j * 16) = make_uint4(pk[j * 4], pk[j * 4 + 1],
                                                     pk[j * 4 + 2], pk[j * 4 + 3]);
        }
        __syncthreads();   // drains: aged B(t+1) vmcnt + As(t+1) lgkm; WAR-safe
    }

    // ---- direct-store epilogue; C/D map hardcoded (m89-verified) ----
#pragma unroll
    for (int i = 0; i < 4; ++i) {
#pragma unroll
        for (int jj = 0; jj < 4; ++jj) {
            const int col = nBase + wn * 64 + jj * 16 + mr;
            const float b2 = bias2[col];
#pragma unroll
            for (int r = 0; r < 4; ++r) {
                const int row = mBase + wm * 64 + i * 16 + quad * 4 + r;
                out[(size_t)row * OUT_F + col] = acc[i][jj][r] + b2;
            }
        }
    }
}

// ---------------- launch ----------------

extern "C" void kernel_launch(void* const* d_in, const int* in_sizes, int n_in,
                              void* d_out, int out_size, void* d_ws, size_t ws_size,
                              hipStream_t stream)
{
    (void)out_size; (void)ws_size;
    const float* x    = (const float*)d_in[0];
    const float* W    = (const float*)d_in[1];
    const float* C    = (const float*)d_in[2];
    const float* bias = (const float*)d_in[3];
    for (int i = 0; i < n_in; ++i) {
        if      (in_sizes[i] == BATCH * IN_F)     x    = (const float*)d_in[i];
        else if (in_sizes[i] == OUT_F * IN_F)     W    = (const float*)d_in[i];
        else if (in_sizes[i] == OUT_F * IN_F * 6) C    = (const float*)d_in[i];
        else if (in_sizes[i] == OUT_F)            bias = (const float*)d_in[i];
    }
    float* out = (float*)d_out;
    char* ws = (char*)d_ws;
    __hip_bfloat16* Waug  = (__hip_bfloat16*)ws;
    float*          bias2 = (float*)(ws + BIAS2_OFF);

    // 152 KB dynamic LDS opt-in (gfx950 supports up to 160 KB; 144 KB proven r1,
    // 160 KB proven by AITER fmha on this chip).
    static bool smem_attr_done = false;
    if (!smem_attr_done) {
        (void)hipFuncSetAttribute((const void*)gemm_kan,
                                  hipFuncAttributeMaxDynamicSharedMemorySize,
                                  SMEM_B);
        smem_attr_done = true;
    }

    prep_w<<<dim3(OUT_F), dim3(256), 0, stream>>>(W, C, bias, Waug, bias2);
    gemm_kan<<<dim3(BATCH / 256, OUT_F / 128), dim3(512), SMEM_B, stream>>>(
        x, Waug, bias2, out);
}